// Round 1
// baseline (227.907 us; speedup 1.0000x reference)
//
#include <hip/hip_runtime.h>

#pragma clang fp contract(off)

#define B_   512
#define N_   16384
#define A_   64
#define TPB  1024
#define CAP  2048

// -------- Kernel 1: centroid per batch, replicating numpy reduction orders --
// atom_pos.sum(-2): numpy reduces a NON-inner axis sequentially (acc += row).
// atom_mask.sum(-1): numpy pairwise_sum, 8-accumulator unrolled for n=64.
__global__ __launch_bounds__(256) void centroid_kernel(
    const float* __restrict__ atom_pos, const float* __restrict__ atom_mask,
    float* __restrict__ cent)
{
#pragma clang fp contract(off)
    int b = blockIdx.x * blockDim.x + threadIdx.x;
    if (b >= B_) return;
    const float* ap = atom_pos + (size_t)b * A_ * 3;
    const float* am = atom_mask + (size_t)b * A_;

    float sx = ap[0], sy = ap[1], sz = ap[2];
    for (int a = 1; a < A_; ++a) {
        sx += ap[a * 3 + 0];
        sy += ap[a * 3 + 1];
        sz += ap[a * 3 + 2];
    }

    float r0 = am[0], r1 = am[1], r2 = am[2], r3 = am[3];
    float r4 = am[4], r5 = am[5], r6 = am[6], r7 = am[7];
    for (int i = 8; i < A_; i += 8) {
        r0 += am[i + 0]; r1 += am[i + 1]; r2 += am[i + 2]; r3 += am[i + 3];
        r4 += am[i + 4]; r5 += am[i + 5]; r6 += am[i + 6]; r7 += am[i + 7];
    }
    float ms = ((r0 + r1) + (r2 + r3)) + ((r4 + r5) + (r6 + r7));

    cent[b * 4 + 0] = sx / ms;   // fp32 divide: correctly rounded (HIP default)
    cent[b * 4 + 1] = sy / ms;
    cent[b * 4 + 2] = sz / ms;
}

// -------- Kernel 2: distances + exact top-k select + mask writes ------------
__global__ __launch_bounds__(TPB) void select_kernel(
    const float* __restrict__ pos, const float* __restrict__ mask,
    const int* __restrict__ topk_ptr, const float* __restrict__ cent,
    float* __restrict__ out0, float* __restrict__ out1)
{
#pragma clang fp contract(off)
    __shared__ unsigned short dist16[N_];    // 32 KB: top 16 bits of fp32 dist
    __shared__ unsigned       hist[2048];    // 8 KB: 11-bit prefix histogram
    __shared__ unsigned       hist2[32];     // 5-bit refinement
    __shared__ unsigned       wsum[64];
    __shared__ unsigned       cand_bits[CAP];
    __shared__ unsigned short cand_idx[CAP];
    __shared__ float          s_c[3];
    __shared__ unsigned       s_B11, s_less11, s_P16, s_j, s_ncand, s_k;

    const int tid = threadIdx.x;
    const int b   = blockIdx.x;
    const float* __restrict__ p = pos  + (size_t)b * N_ * 3;
    const float* __restrict__ m = mask + (size_t)b * N_;

    for (int i = tid; i < 2048; i += TPB) hist[i] = 0u;
    if (tid < 32) hist2[tid] = 0u;
    if (tid == 0) {
        s_ncand = 0u;
        s_c[0] = cent[b * 4 + 0];
        s_c[1] = cent[b * 4 + 1];
        s_c[2] = cent[b * 4 + 2];
        int k = *topk_ptr;
        if (k < 0)  k = 0;
        if (k > N_) k = N_;
        s_k = (unsigned)k;
    }
    __syncthreads();

    const float cx = s_c[0], cy = s_c[1], cz = s_c[2];
    const unsigned k = s_k;

    // ---- Phase A: distances (bit-exact to numpy), store prefix, histogram --
    for (int i = tid; i < N_; i += TPB) {
        float px = p[i * 3 + 0], py = p[i * 3 + 1], pz = p[i * 3 + 2];
        float dx = cx - px, dy = cy - py, dz = cz - pz;
        float dx2 = dx * dx, dy2 = dy * dy, dz2 = dz * dz;
        float s = (dx2 + dy2) + dz2;      // numpy sum order over last axis
        s = s + 1e-12f;                   // EPS
        float d = sqrtf(s);               // correctly rounded (HIP default)
        float im = (1.0f - m[i]) * 1e10f;
        d = d + im;
        unsigned bits = __float_as_uint(d);   // monotone for d >= 0
        dist16[i] = (unsigned short)(bits >> 16);
        atomicAdd(&hist[bits >> 21], 1u);
    }
    __syncthreads();

    if (k > 0) {
        // ---- Phase B: find 11-bit bucket containing the k-th smallest -----
        if (tid < 64) {
            unsigned s = 0; const int base = tid * 32;
            for (int i = 0; i < 32; ++i) s += hist[base + i];
            wsum[tid] = s;
        }
        __syncthreads();
        if (tid == 0) {
            unsigned cum = 0; int g = 63;
            for (int t = 0; t < 64; ++t) {
                if (cum + wsum[t] >= k) { g = t; break; }
                cum += wsum[t];
            }
            int b11 = g * 32 + 31;
            for (int i = 0; i < 32; ++i) {
                unsigned h = hist[g * 32 + i];
                if (cum + h >= k) { b11 = g * 32 + i; break; }
                cum += h;
            }
            s_B11 = (unsigned)b11; s_less11 = cum;
        }
        __syncthreads();
        const unsigned B11 = s_B11;

        // ---- Phase C: refine with low 5 bits of the 16-bit prefix ---------
        for (int i = tid; i < N_; i += TPB) {
            unsigned v = dist16[i];
            if ((v >> 5) == B11) atomicAdd(&hist2[v & 31u], 1u);
        }
        __syncthreads();
        if (tid == 0) {
            unsigned cum = s_less11; int sb = 31;
            for (int i = 0; i < 32; ++i) {
                unsigned h = hist2[i];
                if (cum + h >= k) { sb = i; break; }
                cum += h;
            }
            s_P16 = (B11 << 5) | (unsigned)sb;
            s_j   = k - cum;        // how many to take from the ==P16 group
        }
        __syncthreads();
        const unsigned P16 = s_P16;
        const unsigned j   = s_j;

        // ---- Phase D: gather boundary candidates, recompute full bits -----
        for (int i = tid; i < N_; i += TPB) {
            if (dist16[i] == (unsigned short)P16) {
                unsigned w = atomicAdd(&s_ncand, 1u);
                if (w < CAP) {
                    float px = p[i * 3 + 0], py = p[i * 3 + 1], pz = p[i * 3 + 2];
                    float dx = cx - px, dy = cy - py, dz = cz - pz;
                    float dx2 = dx * dx, dy2 = dy * dy, dz2 = dz * dz;
                    float s = (dx2 + dy2) + dz2;
                    s = s + 1e-12f;
                    float d = sqrtf(s);
                    float im = (1.0f - m[i]) * 1e10f;
                    d = d + im;
                    cand_bits[w] = __float_as_uint(d);
                    cand_idx[w]  = (unsigned short)i;
                }
            }
        }
        __syncthreads();

        // ---- Phase E: rank candidates (tie -> lowest index), mark selected -
        const unsigned c = min(s_ncand, (unsigned)CAP);
        for (unsigned t = tid; t < c; t += TPB) {
            unsigned bt = cand_bits[t];
            unsigned it = cand_idx[t];
            unsigned rank = 0;
            for (unsigned u = 0; u < c; ++u) {
                unsigned bu = cand_bits[u];
                rank += (bu < bt) || (bu == bt && (unsigned)cand_idx[u] < it);
            }
            if (rank < j) dist16[it] = 0;   // mark: 0 < P16 always (d >= 1e-6)
        }
        __syncthreads();
    }

    // ---- Phase F: write both output masks ---------------------------------
    const unsigned P16f = (k > 0) ? s_P16 : 0u;
    for (int i = tid; i < N_; i += TPB) {
        bool sel = (k > 0) && ((unsigned)dist16[i] < P16f);
        float mv = m[i];                         // L2-hot re-read
        out0[(size_t)b * N_ + i] = sel ? 0.0f  : mv;
        out1[(size_t)b * N_ + i] = sel ? 32.0f : (1.0f - mv);
    }
}

extern "C" void kernel_launch(void* const* d_in, const int* in_sizes, int n_in,
                              void* d_out, int out_size, void* d_ws, size_t ws_size,
                              hipStream_t stream) {
    const float* pos   = (const float*)d_in[0];   // [B,N,3]
    const float* rmask = (const float*)d_in[1];   // [B,N]
    const float* apos  = (const float*)d_in[2];   // [B,A,3]
    const float* amask = (const float*)d_in[3];   // [B,A]
    // d_in[4] = max_p (unused by the reference outputs)
    const int*   topk  = (const int*)d_in[5];

    float* out0 = (float*)d_out;
    float* out1 = out0 + (size_t)B_ * N_;
    float* cent = (float*)d_ws;                   // B_*4 floats of scratch

    centroid_kernel<<<(B_ + 255) / 256, 256, 0, stream>>>(apos, amask, cent);
    select_kernel<<<B_, TPB, 0, stream>>>(pos, rmask, topk, cent, out0, out1);
}

// Round 2
// 210.659 us; speedup vs baseline: 1.0819x; 1.0819x over previous
//
#include <hip/hip_runtime.h>

#pragma clang fp contract(off)

#define B_   512
#define N_   16384
#define A_   64
#define TPB  1024
#define CAP  2048
#define ITERS 4              // N_ / (TPB*4)

// One block per batch: centroid (bit-exact numpy order) + distances +
// exact top-k select (16-bit radix + boundary rank) + both mask writes.
__global__ __launch_bounds__(TPB) void fused_kernel(
    const float* __restrict__ pos,   const float* __restrict__ mask,
    const float* __restrict__ apos,  const float* __restrict__ amask,
    const int*   __restrict__ topk_ptr,
    float* __restrict__ out0, float* __restrict__ out1)
{
#pragma clang fp contract(off)
    __shared__ unsigned short dist16[N_];     // 32 KB: top-16 bits of dist
    __shared__ unsigned       hist[2048];     // 8 KB: 11-bit prefix histogram
    __shared__ unsigned       hist2[32];      // 5-bit refinement
    __shared__ unsigned       cand_bits[CAP]; // boundary candidates
    __shared__ unsigned short cand_idx[CAP];
    __shared__ float          s_atoms[A_ * 3 + A_];  // 192 pos + 64 mask
    __shared__ float          s_c[3];
    __shared__ unsigned       s_B11, s_less11, s_P16, s_j, s_ncand, s_k;

    const int tid = threadIdx.x;
    const int b   = blockIdx.x;
    const float* __restrict__ p = pos  + (size_t)b * N_ * 3;
    const float* __restrict__ m = mask + (size_t)b * N_;

    // ---- init: zero hists, stage atoms coalesced, load k ------------------
    hist[tid]        = 0u;
    hist[tid + 1024] = 0u;
    if (tid < 32) hist2[tid] = 0u;
    if (tid < 256)
        s_atoms[tid] = (tid < 192) ? apos[(size_t)b * 192 + tid]
                                   : amask[(size_t)b * 64 + (tid - 192)];
    if (tid == 0) {
        s_ncand = 0u;
        int kk = *topk_ptr;
        if (kk < 0)  kk = 0;
        if (kk > N_) kk = N_;
        s_k = (unsigned)kk;
    }
    __syncthreads();

    // ---- centroid: lanes 0..2 = component sums (numpy sequential axis=-2),
    //      lane 3 = mask pairwise-8 sum (numpy pairwise for n=64) ----------
    if (tid < 64) {
        float comp = 0.0f, ms = 0.0f;
        if (tid < 3) {
            comp = s_atoms[tid];
            for (int a = 1; a < A_; ++a) comp += s_atoms[a * 3 + tid];
        }
        if (tid == 3) {
            const float* am = s_atoms + 192;
            float r0 = am[0], r1 = am[1], r2 = am[2], r3 = am[3];
            float r4 = am[4], r5 = am[5], r6 = am[6], r7 = am[7];
            for (int i = 8; i < A_; i += 8) {
                r0 += am[i + 0]; r1 += am[i + 1]; r2 += am[i + 2]; r3 += am[i + 3];
                r4 += am[i + 4]; r5 += am[i + 5]; r6 += am[i + 6]; r7 += am[i + 7];
            }
            ms = ((r0 + r1) + (r2 + r3)) + ((r4 + r5) + (r6 + r7));
        }
        ms = __shfl(ms, 3, 64);
        if (tid < 3) s_c[tid] = comp / ms;   // correctly-rounded fp32 divide
    }
    __syncthreads();

    const float cx = s_c[0], cy = s_c[1], cz = s_c[2];
    const unsigned k = s_k;

    // ---- Phase A: distances (bit-exact), keep bits+mask in registers ------
    unsigned rbits[ITERS * 4];
    float    rm[ITERS * 4];
#pragma unroll
    for (int it = 0; it < ITERS; ++it) {
        const int i0 = it * (TPB * 4) + tid * 4;
        const float4 pa = *(const float4*)(p + (size_t)i0 * 3);
        const float4 pb = *(const float4*)(p + (size_t)i0 * 3 + 4);
        const float4 pc = *(const float4*)(p + (size_t)i0 * 3 + 8);
        const float4 mv = *(const float4*)(m + i0);
        const float px[4] = {pa.x, pa.w, pb.z, pc.y};
        const float py[4] = {pa.y, pb.x, pb.w, pc.z};
        const float pz[4] = {pa.z, pb.y, pc.x, pc.w};
        const float mm[4] = {mv.x, mv.y, mv.z, mv.w};
        unsigned short loc[4];
#pragma unroll
        for (int j = 0; j < 4; ++j) {
            float dx = cx - px[j], dy = cy - py[j], dz = cz - pz[j];
            float dx2 = dx * dx, dy2 = dy * dy, dz2 = dz * dz;
            float s = (dx2 + dy2) + dz2;     // numpy sum order (no FMA)
            s = s + 1e-12f;
            float d = sqrtf(s);              // correctly rounded
            float im = (1.0f - mm[j]) * 1e10f;
            d = d + im;
            const unsigned bits = __float_as_uint(d);  // monotone, d >= 0
            rbits[it * 4 + j] = bits;
            rm[it * 4 + j]    = mm[j];
            loc[j] = (unsigned short)(bits >> 16);
            atomicAdd(&hist[bits >> 21], 1u);
        }
        *(ushort4*)&dist16[i0] = make_ushort4(loc[0], loc[1], loc[2], loc[3]);
    }
    __syncthreads();

    if (k > 0) {
        // ---- Phase B: wave-0 shuffle scan finds the 11-bit bucket ---------
        if (tid < 64) {
            unsigned s = 0;
#pragma unroll
            for (int i = 0; i < 32; ++i) s += hist[tid * 32 + i];
            unsigned incl = s;
#pragma unroll
            for (int off = 1; off < 64; off <<= 1) {
                unsigned v = (unsigned)__shfl_up((int)incl, off, 64);
                if (tid >= off) incl += v;
            }
            unsigned long long bal = __ballot(incl >= k);
            const int g = __ffsll(bal) - 1;
            const unsigned cum1 = (unsigned)__shfl((int)(incl - s), g, 64);

            unsigned h2 = (tid < 32) ? hist[g * 32 + tid] : 0u;
            unsigned incl2 = h2;
#pragma unroll
            for (int off = 1; off < 64; off <<= 1) {
                unsigned v = (unsigned)__shfl_up((int)incl2, off, 64);
                if (tid >= off) incl2 += v;
            }
            unsigned long long bal2 = __ballot(tid < 32 && (cum1 + incl2 >= k));
            const int sb = __ffsll(bal2) - 1;
            const unsigned cum2 = cum1 + (unsigned)__shfl((int)(incl2 - h2), sb, 64);
            if (tid == 0) { s_B11 = (unsigned)(g * 32 + sb); s_less11 = cum2; }
        }
        __syncthreads();
        const unsigned B11 = s_B11;

        // ---- Phase C: refine low-5 bits (from registers, no re-read) ------
#pragma unroll
        for (int x = 0; x < ITERS * 4; ++x) {
            const unsigned v = rbits[x] >> 16;
            if ((v >> 5) == B11) atomicAdd(&hist2[v & 31u], 1u);
        }
        __syncthreads();
        if (tid < 64) {
            unsigned h = (tid < 32) ? hist2[tid] : 0u;
            unsigned incl = h;
#pragma unroll
            for (int off = 1; off < 64; off <<= 1) {
                unsigned v = (unsigned)__shfl_up((int)incl, off, 64);
                if (tid >= off) incl += v;
            }
            const unsigned less11 = s_less11;
            unsigned long long bal = __ballot(tid < 32 && (less11 + incl >= k));
            const int sb = __ffsll(bal) - 1;
            const unsigned cumx = less11 + (unsigned)__shfl((int)(incl - h), sb, 64);
            if (tid == 0) { s_P16 = (B11 << 5) | (unsigned)sb; s_j = k - cumx; }
        }
        __syncthreads();
        const unsigned P16 = s_P16;
        const unsigned j   = s_j;

        // ---- Phase D: gather boundary candidates from registers -----------
#pragma unroll
        for (int it = 0; it < ITERS; ++it) {
#pragma unroll
            for (int jj = 0; jj < 4; ++jj) {
                const unsigned bits = rbits[it * 4 + jj];
                if ((bits >> 16) == P16) {
                    const unsigned w = atomicAdd(&s_ncand, 1u);
                    if (w < CAP) {
                        cand_bits[w] = bits;
                        cand_idx[w]  = (unsigned short)(it * (TPB * 4) + tid * 4 + jj);
                    }
                }
            }
        }
        __syncthreads();

        // ---- Phase E: rank candidates (tie -> lowest index), mark ---------
        const unsigned c = min(s_ncand, (unsigned)CAP);
        for (unsigned t = tid; t < c; t += TPB) {
            const unsigned bt = cand_bits[t];
            const unsigned it = cand_idx[t];
            unsigned rank = 0;
            for (unsigned u = 0; u < c; ++u) {
                const unsigned bu = cand_bits[u];
                rank += (bu < bt) || (bu == bt && (unsigned)cand_idx[u] < it);
            }
            if (rank < j) dist16[it] = 0;   // 0 < P16 always (d >= 1e-6)
        }
        __syncthreads();
    }

    // ---- Phase F: write both masks (mask values from registers) -----------
    const unsigned P16f = (k > 0) ? s_P16 : 0u;
#pragma unroll
    for (int it = 0; it < ITERS; ++it) {
        const int i0 = it * (TPB * 4) + tid * 4;
        const ushort4 dv = *(const ushort4*)&dist16[i0];
        const unsigned short dvs[4] = {dv.x, dv.y, dv.z, dv.w};
        float4 o0, o1;
        float* o0p = &o0.x; float* o1p = &o1.x;
#pragma unroll
        for (int jj = 0; jj < 4; ++jj) {
            const bool sel = (unsigned)dvs[jj] < P16f;
            const float mv = rm[it * 4 + jj];
            o0p[jj] = sel ? 0.0f  : mv;
            o1p[jj] = sel ? 32.0f : (1.0f - mv);
        }
        *(float4*)(out0 + (size_t)b * N_ + i0) = o0;
        *(float4*)(out1 + (size_t)b * N_ + i0) = o1;
    }
}

extern "C" void kernel_launch(void* const* d_in, const int* in_sizes, int n_in,
                              void* d_out, int out_size, void* d_ws, size_t ws_size,
                              hipStream_t stream) {
    const float* pos   = (const float*)d_in[0];   // [B,N,3]
    const float* rmask = (const float*)d_in[1];   // [B,N]
    const float* apos  = (const float*)d_in[2];   // [B,A,3]
    const float* amask = (const float*)d_in[3];   // [B,A]
    // d_in[4] = max_p (unused by the reference outputs)
    const int*   topk  = (const int*)d_in[5];

    float* out0 = (float*)d_out;
    float* out1 = out0 + (size_t)B_ * N_;

    fused_kernel<<<B_, TPB, 0, stream>>>(pos, rmask, apos, amask, topk, out0, out1);
}